// Round 1
// 430.776 us; speedup vs baseline: 1.1206x; 1.1206x over previous
//
#include <hip/hip_runtime.h>
#include <hip/hip_bf16.h>

// Problem: B=4096, N=64, FIN=256, D1=512, D2=128.
// Algebraic restructuring of the attention (exact, not approximate):
//   alpha[b,n] = x_b . (o_bn@W1+b1) = o_bn . z_b + const_b,  z = x @ W1^T
//     (const_b = x_b.b1 is shift-invariant under softmax -> dropped exactly)
//   c_b = sum_n beta_n (o_bn@W1+b1) = (sum_n beta_n o_bn) @ W1 + b1  (sum beta = 1)
// => the per-batch [64,256]@[256,512] GEMM (34.4 GFLOP) is never computed.
// Pipeline: prep -> k_x (x=obs@W1+b1) -> k_z (z=x@W1^T) -> k_attn (pure fp32,
// memory-bound streaming of `others`, obar out) -> k_c (c=obar@W1+b1) -> k_head.

typedef unsigned short u16;
typedef __bf16 bf16x8 __attribute__((ext_vector_type(8)));
typedef float f32x4 __attribute__((ext_vector_type(4)));

#define FIN 256
#define D1  512
#define D2  128
#define NNA 64
#define NEGV -10000000.0f

__device__ __forceinline__ float bf2f(u16 u) {
  unsigned int i = ((unsigned int)u) << 16;
  return __builtin_bit_cast(float, i);
}
__device__ __forceinline__ u16 f2bf(float f) {
  unsigned int i = __builtin_bit_cast(unsigned int, f);
  return (u16)((i + 0x7FFFu + ((i >> 16) & 1u)) >> 16);
}
__device__ __forceinline__ bf16x8 ld_frag_g(const u16* p) {   // 16B bf16 fragment
  return __builtin_bit_cast(bf16x8, *(const uint4*)p);
}
// load 8 consecutive fp32, convert to bf16x8 fragment
__device__ __forceinline__ bf16x8 ld_frag_f32(const float* p) {
  float4 a = *(const float4*)p, b = *(const float4*)(p + 4);
  u16 s[8];
  s[0] = f2bf(a.x); s[1] = f2bf(a.y); s[2] = f2bf(a.z); s[3] = f2bf(a.w);
  s[4] = f2bf(b.x); s[5] = f2bf(b.y); s[6] = f2bf(b.z); s[7] = f2bf(b.w);
  return __builtin_bit_cast(bf16x8, *(uint4*)s);
}

// ---------------------------------------------------------------------------
// k_prep: W1 [256,512] -> W1p (B-frags, K=256,N=512); W2 [1024,128] -> W2p
// (K=1024,N=128); W1^T [512,256] -> W1tp (B-frags, K=512,N=256).
// Frag layout: P[((kt*NT + nt)*64 + lane)*8 + j] = M[kt*32+(lane>>4)*8+j][nt*16+(lane&15)]
// ---------------------------------------------------------------------------
__global__ __launch_bounds__(256) void k_prep(const float* __restrict__ W1,
                                              const float* __restrict__ W2,
                                              u16* __restrict__ W1p,
                                              u16* __restrict__ W2p,
                                              u16* __restrict__ W1tp) {
  int tid = blockIdx.x * 256 + threadIdx.x;
  if (tid < 131072) {
    int idx = tid;
    int j = idx & 7, lane = (idx >> 3) & 63, nt = (idx >> 9) & 31, kt = idx >> 14;
    int k = kt * 32 + (lane >> 4) * 8 + j;
    int n = nt * 16 + (lane & 15);
    W1p[idx] = f2bf(W1[k * D1 + n]);
  } else if (tid < 163840) {
    int idx = tid - 131072;     // idx < 32768
    int j = idx & 7, lane = (idx >> 3) & 63, nt = (idx >> 9) & 7, kt = idx >> 12;
    int k = kt * 32 + (lane >> 4) * 8 + j;
    int n = nt * 16 + (lane & 15);
    W2p[idx] = f2bf(W2[k * D2 + n]);
  } else {
    int idx = tid - 163840;     // idx < 131072; K=512 (kt<16), N=256 (nt<16)
    int j = idx & 7, lane = (idx >> 3) & 63, nt = (idx >> 9) & 15, kt = idx >> 13;
    int k = kt * 32 + (lane >> 4) * 8 + j;   // k in [0,512)
    int n = nt * 16 + (lane & 15);           // n in [0,256)
    W1tp[idx] = f2bf(W1[n * D1 + k]);        // W1^T[k][n] = W1[n][k]
  }
}

// ---------------------------------------------------------------------------
// k_x: X = obs_x @ W1 + b1 -> bf16, left half of outw [4096,1024].
// Grid (32,4), 256 thr = 4 waves; wave: 32 rows x 128 cols, K=256.
// ---------------------------------------------------------------------------
__global__ __launch_bounds__(256) void k_x(const float* __restrict__ obs,
                                           const u16* __restrict__ W1p,
                                           const float* __restrict__ pb1,
                                           u16* __restrict__ outw) {
  const int w = threadIdx.x >> 6, lane = threadIdx.x & 63;
  const int q = lane >> 4, c0 = lane & 15;
  const int m0 = blockIdx.x * 128 + w * 32;
  const int ntg0 = blockIdx.y * 8;

  f32x4 acc[2][8];
#pragma unroll
  for (int a = 0; a < 2; ++a)
#pragma unroll
    for (int c = 0; c < 8; ++c) acc[a][c] = (f32x4){0.f, 0.f, 0.f, 0.f};

#pragma unroll 1
  for (int kt = 0; kt < 8; ++kt) {
    bf16x8 afr[2], bfr[8];
#pragma unroll
    for (int mt = 0; mt < 2; ++mt)
      afr[mt] = ld_frag_f32(obs + (m0 + mt * 16 + c0) * FIN + kt * 32 + q * 8);
#pragma unroll
    for (int nt = 0; nt < 8; ++nt)
      bfr[nt] = ld_frag_g(W1p + ((kt * 32 + ntg0 + nt) * 64 + lane) * 8);
#pragma unroll
    for (int mt = 0; mt < 2; ++mt)
#pragma unroll
      for (int nt = 0; nt < 8; ++nt)
        acc[mt][nt] = __builtin_amdgcn_mfma_f32_16x16x32_bf16(afr[mt], bfr[nt], acc[mt][nt], 0, 0, 0);
  }

#pragma unroll
  for (int nt = 0; nt < 8; ++nt) {
    const int n = (ntg0 + nt) * 16 + c0;
    const float bias = pb1[n];
#pragma unroll
    for (int mt = 0; mt < 2; ++mt)
#pragma unroll
      for (int i = 0; i < 4; ++i) {
        const int row = m0 + mt * 16 + q * 4 + i;
        outw[row * 1024 + n] = f2bf(acc[mt][nt][i] + bias);
      }
  }
}

// ---------------------------------------------------------------------------
// k_z: z = x @ W1^T -> fp32 zbuf [4096,256].  A = outw left half (bf16).
// Grid (32,2), 256 thr = 4 waves; wave: 32 rows x 128 cols, K=512.
// ---------------------------------------------------------------------------
__global__ __launch_bounds__(256) void k_z(const u16* __restrict__ outw,
                                           const u16* __restrict__ W1tp,
                                           float* __restrict__ zbuf) {
  const int w = threadIdx.x >> 6, lane = threadIdx.x & 63;
  const int q = lane >> 4, c0 = lane & 15;
  const int m0 = blockIdx.x * 128 + w * 32;
  const int ntg0 = blockIdx.y * 8;

  f32x4 acc[2][8];
#pragma unroll
  for (int a = 0; a < 2; ++a)
#pragma unroll
    for (int c = 0; c < 8; ++c) acc[a][c] = (f32x4){0.f, 0.f, 0.f, 0.f};

#pragma unroll 1
  for (int kt = 0; kt < 16; ++kt) {
    bf16x8 afr[2], bfr[8];
#pragma unroll
    for (int mt = 0; mt < 2; ++mt)
      afr[mt] = ld_frag_g(outw + (m0 + mt * 16 + c0) * 1024 + kt * 32 + q * 8);
#pragma unroll
    for (int nt = 0; nt < 8; ++nt)
      bfr[nt] = ld_frag_g(W1tp + ((kt * 16 + ntg0 + nt) * 64 + lane) * 8);
#pragma unroll
    for (int mt = 0; mt < 2; ++mt)
#pragma unroll
      for (int nt = 0; nt < 8; ++nt)
        acc[mt][nt] = __builtin_amdgcn_mfma_f32_16x16x32_bf16(afr[mt], bfr[nt], acc[mt][nt], 0, 0, 0);
  }

#pragma unroll
  for (int nt = 0; nt < 8; ++nt) {
    const int n = (ntg0 + nt) * 16 + c0;
#pragma unroll
    for (int mt = 0; mt < 2; ++mt)
#pragma unroll
      for (int i = 0; i < 4; ++i) {
        const int row = m0 + mt * 16 + q * 4 + i;
        zbuf[row * 256 + n] = acc[mt][nt][i];   // no bias: b1 already inside x
      }
  }
}

// ---------------------------------------------------------------------------
// k_attn: pure fp32, memory-bound. One block (256 thr = 4 waves) per batch b.
//   lane l of wave w holds o[w*16+r, 4l..4l+3] (16 float4 regs, read ONCE).
//   alpha[n] = o_n . z_b / sqrt(512)  (cross-lane shuffle reduce)
//   beta = softmax64(alpha);  obar = sum_n beta_n o_n -> bf16 obarb [4096,256]
// No MFMA, no bf16 staging, no strided-LDS dots.
// ---------------------------------------------------------------------------
__global__ __launch_bounds__(256, 4) void k_attn(const float* __restrict__ others,
                                                 const float* __restrict__ zbuf,
                                                 u16* __restrict__ obarb) {
  __shared__ float s_alpha[64];
  __shared__ float s_beta[64];
  __shared__ float s_part[1024];

  const int tid = threadIdx.x;
  const int b = blockIdx.x;
  const int w = tid >> 6, l = tid & 63;
  const float* src = others + (size_t)b * (NNA * FIN);

  const float4 z4 = *(const float4*)(zbuf + b * 256 + 4 * l);

  float4 o4[16];
#pragma unroll
  for (int r = 0; r < 16; ++r)
    o4[r] = *(const float4*)(src + (w * 16 + r) * 256 + 4 * l);

#pragma unroll
  for (int r = 0; r < 16; ++r) {
    float s = o4[r].x * z4.x + o4[r].y * z4.y + o4[r].z * z4.z + o4[r].w * z4.w;
    s += __shfl_xor(s, 1);  s += __shfl_xor(s, 2);  s += __shfl_xor(s, 4);
    s += __shfl_xor(s, 8);  s += __shfl_xor(s, 16); s += __shfl_xor(s, 32);
    if (l == r) s_alpha[w * 16 + r] = s * 0.04419417382415922f;  // 1/sqrt(512)
  }
  __syncthreads();

  if (tid < 64) {   // wave 0: softmax over the 64 agents
    float v = s_alpha[tid];
    float mx = v;
#pragma unroll
    for (int off = 1; off < 64; off <<= 1) mx = fmaxf(mx, __shfl_xor(mx, off));
    float e = __expf(v - mx);
    float se = e;
#pragma unroll
    for (int off = 1; off < 64; off <<= 1) se += __shfl_xor(se, off);
    s_beta[tid] = e / se;
  }
  __syncthreads();

  float4 p = (float4){0.f, 0.f, 0.f, 0.f};
#pragma unroll
  for (int r = 0; r < 16; ++r) {
    const float bb = s_beta[w * 16 + r];
    p.x += bb * o4[r].x; p.y += bb * o4[r].y; p.z += bb * o4[r].z; p.w += bb * o4[r].w;
  }
  *(float4*)(&s_part[w * 256 + 4 * l]) = p;
  __syncthreads();

  const float v = s_part[tid] + s_part[tid + 256] + s_part[tid + 512] + s_part[tid + 768];
  obarb[(size_t)b * 256 + tid] = f2bf(v);
}

// ---------------------------------------------------------------------------
// k_c: C = obar @ W1 + b1 -> bf16, right half of outw. Same shape as k_x but
// A is already bf16 (obarb [4096,256]). Grid (32,4), wave: 32 rows x 128 cols.
// ---------------------------------------------------------------------------
__global__ __launch_bounds__(256) void k_c(const u16* __restrict__ obarb,
                                           const u16* __restrict__ W1p,
                                           const float* __restrict__ pb1,
                                           u16* __restrict__ outw) {
  const int w = threadIdx.x >> 6, lane = threadIdx.x & 63;
  const int q = lane >> 4, c0 = lane & 15;
  const int m0 = blockIdx.x * 128 + w * 32;
  const int ntg0 = blockIdx.y * 8;

  f32x4 acc[2][8];
#pragma unroll
  for (int a = 0; a < 2; ++a)
#pragma unroll
    for (int c = 0; c < 8; ++c) acc[a][c] = (f32x4){0.f, 0.f, 0.f, 0.f};

#pragma unroll 1
  for (int kt = 0; kt < 8; ++kt) {
    bf16x8 afr[2], bfr[8];
#pragma unroll
    for (int mt = 0; mt < 2; ++mt)
      afr[mt] = ld_frag_g(obarb + (m0 + mt * 16 + c0) * 256 + kt * 32 + q * 8);
#pragma unroll
    for (int nt = 0; nt < 8; ++nt)
      bfr[nt] = ld_frag_g(W1p + ((kt * 32 + ntg0 + nt) * 64 + lane) * 8);
#pragma unroll
    for (int mt = 0; mt < 2; ++mt)
#pragma unroll
      for (int nt = 0; nt < 8; ++nt)
        acc[mt][nt] = __builtin_amdgcn_mfma_f32_16x16x32_bf16(afr[mt], bfr[nt], acc[mt][nt], 0, 0, 0);
  }

#pragma unroll
  for (int nt = 0; nt < 8; ++nt) {
    const int n = (ntg0 + nt) * 16 + c0;
    const float bias = pb1[n];
#pragma unroll
    for (int mt = 0; mt < 2; ++mt)
#pragma unroll
      for (int i = 0; i < 4; ++i) {
        const int row = m0 + mt * 16 + q * 4 + i;
        outw[row * 1024 + 512 + n] = f2bf(acc[mt][nt][i] + bias);
      }
  }
}

// ---------------------------------------------------------------------------
// k_head: logits = softmax(out @ W2 + b2); masked += NEG -> d_out FP32.
// Regridded for parallelism: 256 blocks x 1 wave, 16 rows x 128 cols, K=1024.
// (no __syncthreads needed -> independent waves, all 256 CUs covered)
// ---------------------------------------------------------------------------
__global__ __launch_bounds__(64) void k_head(const u16* __restrict__ outw,
                                             const u16* __restrict__ W2p,
                                             const float* __restrict__ pb2,
                                             const int* __restrict__ mask,
                                             float* __restrict__ out) {
  const int lane = threadIdx.x & 63;
  const int q = lane >> 4, c0 = lane & 15;
  const int m0 = blockIdx.x * 16;

  f32x4 acc[8];
#pragma unroll
  for (int c = 0; c < 8; ++c) acc[c] = (f32x4){0.f, 0.f, 0.f, 0.f};

#pragma unroll 1
  for (int kt = 0; kt < 32; ++kt) {
    bf16x8 afr, bfr[8];
    afr = ld_frag_g(outw + (m0 + c0) * 1024 + kt * 32 + q * 8);
#pragma unroll
    for (int nt = 0; nt < 8; ++nt)
      bfr[nt] = ld_frag_g(W2p + ((kt * 8 + nt) * 64 + lane) * 8);
#pragma unroll
    for (int nt = 0; nt < 8; ++nt)
      acc[nt] = __builtin_amdgcn_mfma_f32_16x16x32_bf16(afr, bfr[nt], acc[nt], 0, 0, 0);
  }

  float b2f[8];
#pragma unroll
  for (int nt = 0; nt < 8; ++nt) b2f[nt] = pb2[nt * 16 + c0];

#pragma unroll
  for (int i = 0; i < 4; ++i) {
    const int row = m0 + q * 4 + i;
    float v[8];
    float mx = -3.0e38f;
#pragma unroll
    for (int nt = 0; nt < 8; ++nt) { v[nt] = acc[nt][i] + b2f[nt]; mx = fmaxf(mx, v[nt]); }
    mx = fmaxf(mx, __shfl_xor(mx, 1)); mx = fmaxf(mx, __shfl_xor(mx, 2));
    mx = fmaxf(mx, __shfl_xor(mx, 4)); mx = fmaxf(mx, __shfl_xor(mx, 8));
    float se = 0.f;
#pragma unroll
    for (int nt = 0; nt < 8; ++nt) { v[nt] = __expf(v[nt] - mx); se += v[nt]; }
    se += __shfl_xor(se, 1); se += __shfl_xor(se, 2);
    se += __shfl_xor(se, 4); se += __shfl_xor(se, 8);
    const float inv = 1.f / se;
#pragma unroll
    for (int nt = 0; nt < 8; ++nt) {
      const int col = nt * 16 + c0;
      float p = fminf(fmaxf(v[nt] * inv, 0.f), 1.f);   // NaN-safe clamp to [0,1]
      float o = mask[row * D2 + col] ? p : (p + NEGV); // fp32, like the reference
      out[row * D2 + col] = o;
    }
  }
}

extern "C" void kernel_launch(void* const* d_in, const int* in_sizes, int n_in,
                              void* d_out, int out_size, void* d_ws, size_t ws_size,
                              hipStream_t stream) {
  const float* obs = (const float*)d_in[0];   // [4096,256] fp32
  const float* oth = (const float*)d_in[1];   // [4096,64,256] fp32
  const int*   msk = (const int*)d_in[2];     // [4096,128] int32
  const float* W1  = (const float*)d_in[3];   // [256,512] fp32
  const float* b1  = (const float*)d_in[4];   // [512] fp32
  const float* W2  = (const float*)d_in[5];   // [1024,128] fp32
  const float* b2  = (const float*)d_in[6];   // [128] fp32
  // d_in[7..10] = W3,b3,W4,b4: dead code (value head deleted in reference)
  float* out = (float*)d_out;                 // [4096,128] fp32

  char* ws = (char*)d_ws;
  u16*   W1p   = (u16*)ws;                      //   262144 B
  u16*   W2p   = (u16*)(ws + 262144);           //    65536 B
  u16*   W1tp  = (u16*)(ws + 327680);           //   262144 B
  u16*   outw  = (u16*)(ws + 589824);           //  8388608 B  [4096,1024] bf16
  float* zbuf  = (float*)(ws + 8978432);        //  4194304 B  [4096,256] fp32
  u16*   obarb = (u16*)(ws + 13172736);         //  2097152 B  [4096,256] bf16
                                                // total ~15.3 MB

  k_prep<<<1152, 256, 0, stream>>>(W1, W2, W1p, W2p, W1tp);
  k_x<<<dim3(32, 4), 256, 0, stream>>>(obs, W1p, b1, outw);
  k_z<<<dim3(32, 2), 256, 0, stream>>>(outw, W1tp, zbuf);
  k_attn<<<4096, 256, 0, stream>>>(oth, zbuf, obarb);
  k_c<<<dim3(32, 4), 256, 0, stream>>>(obarb, W1p, b1, outw);
  k_head<<<256, 64, 0, stream>>>(outw, W2p, b2, msk, out);
}

// Round 2
// 427.246 us; speedup vs baseline: 1.1298x; 1.0083x over previous
//
#include <hip/hip_runtime.h>
#include <hip/hip_bf16.h>

// Problem: B=4096, N=64, FIN=256, D1=512, D2=128.
// Algebraic restructuring of the attention (exact, not approximate):
//   alpha[b,n] = o_bn . z_b (+const),  z = x @ W1^T   (softmax shift-invariant)
//   c_b = (sum_n beta_n o_bn) @ W1 + b1               (sum beta = 1)
// Pipeline (5 dispatches): prep -> k_x (x=obs@W1+b1) -> k_z (z=x@W1^T)
//   -> k_attn (pure fp32 streaming of `others`, obar out)
//   -> k_tail (c=obar@W1+b1 in LDS, head GEMM + softmax + mask, fused).

typedef unsigned short u16;
typedef __bf16 bf16x8 __attribute__((ext_vector_type(8)));
typedef float f32x4 __attribute__((ext_vector_type(4)));

#define FIN 256
#define D1  512
#define D2  128
#define NNA 64
#define NEGV -10000000.0f

__device__ __forceinline__ float bf2f(u16 u) {
  unsigned int i = ((unsigned int)u) << 16;
  return __builtin_bit_cast(float, i);
}
__device__ __forceinline__ u16 f2bf(float f) {
  unsigned int i = __builtin_bit_cast(unsigned int, f);
  return (u16)((i + 0x7FFFu + ((i >> 16) & 1u)) >> 16);
}
__device__ __forceinline__ bf16x8 ld_frag_g(const u16* p) {   // 16B bf16 fragment
  return __builtin_bit_cast(bf16x8, *(const uint4*)p);
}
// load 8 consecutive fp32, convert to bf16x8 fragment
__device__ __forceinline__ bf16x8 ld_frag_f32(const float* p) {
  float4 a = *(const float4*)p, b = *(const float4*)(p + 4);
  u16 s[8];
  s[0] = f2bf(a.x); s[1] = f2bf(a.y); s[2] = f2bf(a.z); s[3] = f2bf(a.w);
  s[4] = f2bf(b.x); s[5] = f2bf(b.y); s[6] = f2bf(b.z); s[7] = f2bf(b.w);
  return __builtin_bit_cast(bf16x8, *(uint4*)s);
}

// ---------------------------------------------------------------------------
// k_prep: W1 [256,512] -> W1p (B-frags, K=256,N=512); W2 [1024,128] -> W2p
// (K=1024,N=128); W1^T [512,256] -> W1tp (B-frags, K=512,N=256).
// Frag layout: P[((kt*NT + nt)*64 + lane)*8 + j] = M[kt*32+(lane>>4)*8+j][nt*16+(lane&15)]
// ---------------------------------------------------------------------------
__global__ __launch_bounds__(256) void k_prep(const float* __restrict__ W1,
                                              const float* __restrict__ W2,
                                              u16* __restrict__ W1p,
                                              u16* __restrict__ W2p,
                                              u16* __restrict__ W1tp) {
  int tid = blockIdx.x * 256 + threadIdx.x;
  if (tid < 131072) {
    int idx = tid;
    int j = idx & 7, lane = (idx >> 3) & 63, nt = (idx >> 9) & 31, kt = idx >> 14;
    int k = kt * 32 + (lane >> 4) * 8 + j;
    int n = nt * 16 + (lane & 15);
    W1p[idx] = f2bf(W1[k * D1 + n]);
  } else if (tid < 163840) {
    int idx = tid - 131072;     // idx < 32768
    int j = idx & 7, lane = (idx >> 3) & 63, nt = (idx >> 9) & 7, kt = idx >> 12;
    int k = kt * 32 + (lane >> 4) * 8 + j;
    int n = nt * 16 + (lane & 15);
    W2p[idx] = f2bf(W2[k * D2 + n]);
  } else {
    int idx = tid - 163840;     // idx < 131072; K=512 (kt<16), N=256 (nt<16)
    int j = idx & 7, lane = (idx >> 3) & 63, nt = (idx >> 9) & 15, kt = idx >> 13;
    int k = kt * 32 + (lane >> 4) * 8 + j;   // k in [0,512)
    int n = nt * 16 + (lane & 15);           // n in [0,256)
    W1tp[idx] = f2bf(W1[n * D1 + k]);        // W1^T[k][n] = W1[n][k]
  }
}

// ---------------------------------------------------------------------------
// k_x: X = obs_x @ W1 + b1 -> bf16 outw [4096,512].
// 1-wave blocks for max CU spread: grid (128,4), 64 thr; wave: 32r x 128c, K=256.
// ---------------------------------------------------------------------------
__global__ __launch_bounds__(64) void k_x(const float* __restrict__ obs,
                                          const u16* __restrict__ W1p,
                                          const float* __restrict__ pb1,
                                          u16* __restrict__ outw) {
  const int lane = threadIdx.x & 63;
  const int q = lane >> 4, c0 = lane & 15;
  const int m0 = blockIdx.x * 32;
  const int ntg0 = blockIdx.y * 8;

  f32x4 acc[2][8];
#pragma unroll
  for (int a = 0; a < 2; ++a)
#pragma unroll
    for (int c = 0; c < 8; ++c) acc[a][c] = (f32x4){0.f, 0.f, 0.f, 0.f};

#pragma unroll 1
  for (int kt = 0; kt < 8; ++kt) {
    bf16x8 afr[2], bfr[8];
#pragma unroll
    for (int mt = 0; mt < 2; ++mt)
      afr[mt] = ld_frag_f32(obs + (m0 + mt * 16 + c0) * FIN + kt * 32 + q * 8);
#pragma unroll
    for (int nt = 0; nt < 8; ++nt)
      bfr[nt] = ld_frag_g(W1p + ((kt * 32 + ntg0 + nt) * 64 + lane) * 8);
#pragma unroll
    for (int mt = 0; mt < 2; ++mt)
#pragma unroll
      for (int nt = 0; nt < 8; ++nt)
        acc[mt][nt] = __builtin_amdgcn_mfma_f32_16x16x32_bf16(afr[mt], bfr[nt], acc[mt][nt], 0, 0, 0);
  }

#pragma unroll
  for (int nt = 0; nt < 8; ++nt) {
    const int n = (ntg0 + nt) * 16 + c0;
    const float bias = pb1[n];
#pragma unroll
    for (int mt = 0; mt < 2; ++mt)
#pragma unroll
      for (int i = 0; i < 4; ++i) {
        const int row = m0 + mt * 16 + q * 4 + i;
        outw[row * 512 + n] = f2bf(acc[mt][nt][i] + bias);
      }
  }
}

// ---------------------------------------------------------------------------
// k_z: z = x @ W1^T -> fp32 zbuf [4096,256].  A = outw (bf16), K=512.
// grid (128,2), 64 thr; wave: 32 rows x 128 cols.
// ---------------------------------------------------------------------------
__global__ __launch_bounds__(64) void k_z(const u16* __restrict__ outw,
                                          const u16* __restrict__ W1tp,
                                          float* __restrict__ zbuf) {
  const int lane = threadIdx.x & 63;
  const int q = lane >> 4, c0 = lane & 15;
  const int m0 = blockIdx.x * 32;
  const int ntg0 = blockIdx.y * 8;

  f32x4 acc[2][8];
#pragma unroll
  for (int a = 0; a < 2; ++a)
#pragma unroll
    for (int c = 0; c < 8; ++c) acc[a][c] = (f32x4){0.f, 0.f, 0.f, 0.f};

#pragma unroll 1
  for (int kt = 0; kt < 16; ++kt) {
    bf16x8 afr[2], bfr[8];
#pragma unroll
    for (int mt = 0; mt < 2; ++mt)
      afr[mt] = ld_frag_g(outw + (m0 + mt * 16 + c0) * 512 + kt * 32 + q * 8);
#pragma unroll
    for (int nt = 0; nt < 8; ++nt)
      bfr[nt] = ld_frag_g(W1tp + ((kt * 16 + ntg0 + nt) * 64 + lane) * 8);
#pragma unroll
    for (int mt = 0; mt < 2; ++mt)
#pragma unroll
      for (int nt = 0; nt < 8; ++nt)
        acc[mt][nt] = __builtin_amdgcn_mfma_f32_16x16x32_bf16(afr[mt], bfr[nt], acc[mt][nt], 0, 0, 0);
  }

#pragma unroll
  for (int nt = 0; nt < 8; ++nt) {
    const int n = (ntg0 + nt) * 16 + c0;
#pragma unroll
    for (int mt = 0; mt < 2; ++mt)
#pragma unroll
      for (int i = 0; i < 4; ++i) {
        const int row = m0 + mt * 16 + q * 4 + i;
        zbuf[row * 256 + n] = acc[mt][nt][i];   // no bias: b1 already inside x
      }
  }
}

// ---------------------------------------------------------------------------
// k_attn: pure fp32, memory-bound. One block (256 thr = 4 waves) per batch b.
//   lane l of wave w holds o[w*16+r, 4l..4l+3] (16 float4 regs, read ONCE).
//   alpha[n] = o_n . z_b / sqrt(512)  (cross-lane shuffle reduce)
//   beta = softmax64(alpha);  obar = sum_n beta_n o_n -> bf16 obarb [4096,256]
// ---------------------------------------------------------------------------
__global__ __launch_bounds__(256, 4) void k_attn(const float* __restrict__ others,
                                                 const float* __restrict__ zbuf,
                                                 u16* __restrict__ obarb) {
  __shared__ float s_alpha[64];
  __shared__ float s_beta[64];
  __shared__ float s_part[1024];

  const int tid = threadIdx.x;
  const int b = blockIdx.x;
  const int w = tid >> 6, l = tid & 63;
  const float* src = others + (size_t)b * (NNA * FIN);

  const float4 z4 = *(const float4*)(zbuf + b * 256 + 4 * l);

  float4 o4[16];
#pragma unroll
  for (int r = 0; r < 16; ++r)
    o4[r] = *(const float4*)(src + (w * 16 + r) * 256 + 4 * l);

#pragma unroll
  for (int r = 0; r < 16; ++r) {
    float s = o4[r].x * z4.x + o4[r].y * z4.y + o4[r].z * z4.z + o4[r].w * z4.w;
    s += __shfl_xor(s, 1);  s += __shfl_xor(s, 2);  s += __shfl_xor(s, 4);
    s += __shfl_xor(s, 8);  s += __shfl_xor(s, 16); s += __shfl_xor(s, 32);
    if (l == r) s_alpha[w * 16 + r] = s * 0.04419417382415922f;  // 1/sqrt(512)
  }
  __syncthreads();

  if (tid < 64) {   // wave 0: softmax over the 64 agents
    float v = s_alpha[tid];
    float mx = v;
#pragma unroll
    for (int off = 1; off < 64; off <<= 1) mx = fmaxf(mx, __shfl_xor(mx, off));
    float e = __expf(v - mx);
    float se = e;
#pragma unroll
    for (int off = 1; off < 64; off <<= 1) se += __shfl_xor(se, off);
    s_beta[tid] = e / se;
  }
  __syncthreads();

  float4 p = (float4){0.f, 0.f, 0.f, 0.f};
#pragma unroll
  for (int r = 0; r < 16; ++r) {
    const float bb = s_beta[w * 16 + r];
    p.x += bb * o4[r].x; p.y += bb * o4[r].y; p.z += bb * o4[r].z; p.w += bb * o4[r].w;
  }
  *(float4*)(&s_part[w * 256 + 4 * l]) = p;
  __syncthreads();

  const float v = s_part[tid] + s_part[tid + 256] + s_part[tid + 512] + s_part[tid + 768];
  obarb[(size_t)b * 256 + tid] = f2bf(v);
}

// ---------------------------------------------------------------------------
// k_tail: fused c + head. Grid 256 x 128 thr (2 waves), 16 rows per block.
// Phase 1: c[16,512] = obar@W1 + b1 (bf16) -> LDS c_s (stride 520: 2-way
//          banking = free). Wave w: 16 rows x cols [w*256, w*256+256), K=256.
// Phase 2: head 16x128 K=1024. A-frags: k<512 from outw (x, global),
//          k>=512 from LDS c_s. Wave w: cols [w*64, w*64+64).
//          Row softmax across the 2 waves via tiny LDS max/sum exchange.
// ---------------------------------------------------------------------------
__global__ __launch_bounds__(128) void k_tail(const u16* __restrict__ outw,
                                              const u16* __restrict__ obarb,
                                              const u16* __restrict__ W1p,
                                              const float* __restrict__ pb1,
                                              const u16* __restrict__ W2p,
                                              const float* __restrict__ pb2,
                                              const int* __restrict__ mask,
                                              float* __restrict__ out) {
  __shared__ __align__(16) u16 c_s[16 * 520];
  __shared__ float s_mx[2][16];
  __shared__ float s_se[2][16];

  const int tid = threadIdx.x;
  const int w = tid >> 6, lane = tid & 63;
  const int q = lane >> 4, c0 = lane & 15;
  const int m0 = blockIdx.x * 16;

  // ---- phase 1: c chunk 16 x 256 per wave ----
  {
    f32x4 acc[16];
#pragma unroll
    for (int c = 0; c < 16; ++c) acc[c] = (f32x4){0.f, 0.f, 0.f, 0.f};

#pragma unroll 1
    for (int kt = 0; kt < 8; ++kt) {
      bf16x8 afr = ld_frag_g(obarb + (m0 + c0) * 256 + kt * 32 + q * 8);
      bf16x8 bfr[16];
#pragma unroll
      for (int nt = 0; nt < 16; ++nt)
        bfr[nt] = ld_frag_g(W1p + ((kt * 32 + w * 16 + nt) * 64 + lane) * 8);
#pragma unroll
      for (int nt = 0; nt < 16; ++nt)
        acc[nt] = __builtin_amdgcn_mfma_f32_16x16x32_bf16(afr, bfr[nt], acc[nt], 0, 0, 0);
    }

#pragma unroll
    for (int nt = 0; nt < 16; ++nt) {
      const int n = w * 256 + nt * 16 + c0;
      const float bias = pb1[n];
#pragma unroll
      for (int i = 0; i < 4; ++i)
        c_s[(q * 4 + i) * 520 + n] = f2bf(acc[nt][i] + bias);
    }
  }
  __syncthreads();

  // ---- phase 2: head 16 x 64 per wave, K = 1024 ----
  f32x4 acc[4];
#pragma unroll
  for (int c = 0; c < 4; ++c) acc[c] = (f32x4){0.f, 0.f, 0.f, 0.f};

#pragma unroll 1
  for (int kt = 0; kt < 16; ++kt) {     // k in [0,512): x from global
    bf16x8 afr = ld_frag_g(outw + (m0 + c0) * 512 + kt * 32 + q * 8);
    bf16x8 bfr[4];
#pragma unroll
    for (int nt = 0; nt < 4; ++nt)
      bfr[nt] = ld_frag_g(W2p + ((kt * 8 + w * 4 + nt) * 64 + lane) * 8);
#pragma unroll
    for (int nt = 0; nt < 4; ++nt)
      acc[nt] = __builtin_amdgcn_mfma_f32_16x16x32_bf16(afr, bfr[nt], acc[nt], 0, 0, 0);
  }
#pragma unroll 1
  for (int kt = 0; kt < 16; ++kt) {     // k in [512,1024): c from LDS
    bf16x8 afr = __builtin_bit_cast(bf16x8, *(const uint4*)(c_s + c0 * 520 + kt * 32 + q * 8));
    bf16x8 bfr[4];
#pragma unroll
    for (int nt = 0; nt < 4; ++nt)
      bfr[nt] = ld_frag_g(W2p + (((kt + 16) * 8 + w * 4 + nt) * 64 + lane) * 8);
#pragma unroll
    for (int nt = 0; nt < 4; ++nt)
      acc[nt] = __builtin_amdgcn_mfma_f32_16x16x32_bf16(afr, bfr[nt], acc[nt], 0, 0, 0);
  }

  float b2f[4];
#pragma unroll
  for (int nt = 0; nt < 4; ++nt) b2f[nt] = pb2[(w * 4 + nt) * 16 + c0];

  float vv[4][4];
  // wave-local row max (over this wave's 64 cols) -> LDS
#pragma unroll
  for (int i = 0; i < 4; ++i) {
    float mx = -3.0e38f;
#pragma unroll
    for (int nt = 0; nt < 4; ++nt) { vv[i][nt] = acc[nt][i] + b2f[nt]; mx = fmaxf(mx, vv[i][nt]); }
    mx = fmaxf(mx, __shfl_xor(mx, 1)); mx = fmaxf(mx, __shfl_xor(mx, 2));
    mx = fmaxf(mx, __shfl_xor(mx, 4)); mx = fmaxf(mx, __shfl_xor(mx, 8));
    if (c0 == 0) s_mx[w][q * 4 + i] = mx;
  }
  __syncthreads();

  // exp with global row max, wave-local sum -> LDS
#pragma unroll
  for (int i = 0; i < 4; ++i) {
    const int r = q * 4 + i;
    const float mx = fmaxf(s_mx[0][r], s_mx[1][r]);
    float se = 0.f;
#pragma unroll
    for (int nt = 0; nt < 4; ++nt) { vv[i][nt] = __expf(vv[i][nt] - mx); se += vv[i][nt]; }
    se += __shfl_xor(se, 1); se += __shfl_xor(se, 2);
    se += __shfl_xor(se, 4); se += __shfl_xor(se, 8);
    if (c0 == 0) s_se[w][q * 4 + i] = se;
  }
  __syncthreads();

#pragma unroll
  for (int i = 0; i < 4; ++i) {
    const int r = q * 4 + i;
    const int row = m0 + r;
    const float inv = 1.f / (s_se[0][r] + s_se[1][r]);
#pragma unroll
    for (int nt = 0; nt < 4; ++nt) {
      const int col = (w * 4 + nt) * 16 + c0;
      float p = fminf(fmaxf(vv[i][nt] * inv, 0.f), 1.f);   // NaN-safe clamp to [0,1]
      float o = mask[row * D2 + col] ? p : (p + NEGV);     // fp32, like the reference
      out[row * D2 + col] = o;
    }
  }
}

extern "C" void kernel_launch(void* const* d_in, const int* in_sizes, int n_in,
                              void* d_out, int out_size, void* d_ws, size_t ws_size,
                              hipStream_t stream) {
  const float* obs = (const float*)d_in[0];   // [4096,256] fp32
  const float* oth = (const float*)d_in[1];   // [4096,64,256] fp32
  const int*   msk = (const int*)d_in[2];     // [4096,128] int32
  const float* W1  = (const float*)d_in[3];   // [256,512] fp32
  const float* b1  = (const float*)d_in[4];   // [512] fp32
  const float* W2  = (const float*)d_in[5];   // [1024,128] fp32
  const float* b2  = (const float*)d_in[6];   // [128] fp32
  // d_in[7..10] = W3,b3,W4,b4: dead code (value head deleted in reference)
  float* out = (float*)d_out;                 // [4096,128] fp32

  char* ws = (char*)d_ws;
  u16*   W1p   = (u16*)ws;                      //   262144 B
  u16*   W2p   = (u16*)(ws + 262144);           //    65536 B
  u16*   W1tp  = (u16*)(ws + 327680);           //   262144 B
  u16*   outw  = (u16*)(ws + 589824);           //  4194304 B  [4096,512] bf16 (x only)
  float* zbuf  = (float*)(ws + 4784128);        //  4194304 B  [4096,256] fp32
  u16*   obarb = (u16*)(ws + 8978432);          //  2097152 B  [4096,256] bf16
                                                // total ~11.1 MB

  k_prep<<<1152, 256, 0, stream>>>(W1, W2, W1p, W2p, W1tp);
  k_x<<<dim3(128, 4), 64, 0, stream>>>(obs, W1p, b1, outw);
  k_z<<<dim3(128, 2), 64, 0, stream>>>(outw, W1tp, zbuf);
  k_attn<<<4096, 256, 0, stream>>>(oth, zbuf, obarb);
  k_tail<<<256, 128, 0, stream>>>(outw, obarb, W1p, b1, W2p, b2, msk, out);
}

// Round 4
// 391.511 us; speedup vs baseline: 1.2330x; 1.0913x over previous
//
#include <hip/hip_runtime.h>
#include <hip/hip_bf16.h>

// Problem: B=4096, N=64, FIN=256, D1=512, D2=128.
// Algebraic restructuring of the attention (exact, not approximate):
//   alpha[b,n] = o_bn . z_b (+const),  z = x @ W1^T   (softmax shift-invariant)
//   c_b = (sum_n beta_n o_bn) @ W1 + b1               (sum beta = 1)
// Pipeline (4 dispatches): prep -> k_xz (x=obs@W1+b1, z=x@W1^T fused via LDS)
//   -> k_attn (pure fp32 streaming of `others`, log-tree alpha reduce, obar out)
//   -> k_tail (c=obar@W1+b1 in LDS, head GEMM + softmax + mask, fused).

typedef unsigned short u16;
typedef __bf16 bf16x8 __attribute__((ext_vector_type(8)));
typedef float f32x4 __attribute__((ext_vector_type(4)));

#define FIN 256
#define D1  512
#define D2  128
#define NNA 64
#define NEGV -10000000.0f

__device__ __forceinline__ float bf2f(u16 u) {
  unsigned int i = ((unsigned int)u) << 16;
  return __builtin_bit_cast(float, i);
}
__device__ __forceinline__ u16 f2bf(float f) {
  unsigned int i = __builtin_bit_cast(unsigned int, f);
  return (u16)((i + 0x7FFFu + ((i >> 16) & 1u)) >> 16);
}
__device__ __forceinline__ bf16x8 ld_frag_g(const u16* p) {   // 16B bf16 fragment
  return __builtin_bit_cast(bf16x8, *(const uint4*)p);
}
// load 8 consecutive fp32, convert to bf16x8 fragment
__device__ __forceinline__ bf16x8 ld_frag_f32(const float* p) {
  float4 a = *(const float4*)p, b = *(const float4*)(p + 4);
  u16 s[8];
  s[0] = f2bf(a.x); s[1] = f2bf(a.y); s[2] = f2bf(a.z); s[3] = f2bf(a.w);
  s[4] = f2bf(b.x); s[5] = f2bf(b.y); s[6] = f2bf(b.z); s[7] = f2bf(b.w);
  return __builtin_bit_cast(bf16x8, *(uint4*)s);
}
// streaming read-once 16B load (ext_vector type: valid for the builtin)
__device__ __forceinline__ f32x4 ldnt(const float* p) {
  return __builtin_nontemporal_load((const f32x4*)p);
}

// ---------------------------------------------------------------------------
// k_prep: W1 [256,512] -> W1p (B-frags, K=256,N=512); W2 [1024,128] -> W2p
// (K=1024,N=128); W1^T [512,256] -> W1tp (B-frags, K=512,N=256).
// Frag layout: P[((kt*NT + nt)*64 + lane)*8 + j] = M[kt*32+(lane>>4)*8+j][nt*16+(lane&15)]
// ---------------------------------------------------------------------------
__global__ __launch_bounds__(256) void k_prep(const float* __restrict__ W1,
                                              const float* __restrict__ W2,
                                              u16* __restrict__ W1p,
                                              u16* __restrict__ W2p,
                                              u16* __restrict__ W1tp) {
  int tid = blockIdx.x * 256 + threadIdx.x;
  if (tid < 131072) {
    int idx = tid;
    int j = idx & 7, lane = (idx >> 3) & 63, nt = (idx >> 9) & 31, kt = idx >> 14;
    int k = kt * 32 + (lane >> 4) * 8 + j;
    int n = nt * 16 + (lane & 15);
    W1p[idx] = f2bf(W1[k * D1 + n]);
  } else if (tid < 163840) {
    int idx = tid - 131072;     // idx < 32768
    int j = idx & 7, lane = (idx >> 3) & 63, nt = (idx >> 9) & 7, kt = idx >> 12;
    int k = kt * 32 + (lane >> 4) * 8 + j;
    int n = nt * 16 + (lane & 15);
    W2p[idx] = f2bf(W2[k * D2 + n]);
  } else {
    int idx = tid - 163840;     // idx < 131072; K=512 (kt<16), N=256 (nt<16)
    int j = idx & 7, lane = (idx >> 3) & 63, nt = (idx >> 9) & 15, kt = idx >> 13;
    int k = kt * 32 + (lane >> 4) * 8 + j;   // k in [0,512)
    int n = nt * 16 + (lane & 15);           // n in [0,256)
    W1tp[idx] = f2bf(W1[n * D1 + k]);        // W1^T[k][n] = W1[n][k]
  }
}

// ---------------------------------------------------------------------------
// k_xz: fused x + z. Grid 256 x 256 thr (4 waves), 16 rows per block.
// Phase A: x[16,512] = obs@W1 + b1; wave w -> cols [w*128, w*128+128), K=256.
//          bf16 x written to global outw AND to LDS x_s (stride 520).
// Phase B: z[16,256] = x@W1^T (K=512); wave w -> cols [w*64, w*64+64).
//          A-frags from LDS (same bf16 values => numerics identical to split).
// ---------------------------------------------------------------------------
__global__ __launch_bounds__(256) void k_xz(const float* __restrict__ obs,
                                            const u16* __restrict__ W1p,
                                            const u16* __restrict__ W1tp,
                                            const float* __restrict__ pb1,
                                            u16* __restrict__ outw,
                                            float* __restrict__ zbuf) {
  __shared__ __align__(16) u16 x_s[16 * 520];

  const int tid = threadIdx.x;
  const int w = tid >> 6, lane = tid & 63;
  const int q = lane >> 4, c0 = lane & 15;
  const int m0 = blockIdx.x * 16;
  const int ntg0 = w * 8;

  // ---- phase A: x chunk 16 x 128 per wave ----
  {
    f32x4 acc[8];
#pragma unroll
    for (int c = 0; c < 8; ++c) acc[c] = (f32x4){0.f, 0.f, 0.f, 0.f};

#pragma unroll 1
    for (int kt = 0; kt < 8; ++kt) {
      bf16x8 afr = ld_frag_f32(obs + (m0 + c0) * FIN + kt * 32 + q * 8);
      bf16x8 bfr[8];
#pragma unroll
      for (int nt = 0; nt < 8; ++nt)
        bfr[nt] = ld_frag_g(W1p + ((kt * 32 + ntg0 + nt) * 64 + lane) * 8);
#pragma unroll
      for (int nt = 0; nt < 8; ++nt)
        acc[nt] = __builtin_amdgcn_mfma_f32_16x16x32_bf16(afr, bfr[nt], acc[nt], 0, 0, 0);
    }

#pragma unroll
    for (int nt = 0; nt < 8; ++nt) {
      const int n = (ntg0 + nt) * 16 + c0;
      const float bias = pb1[n];
#pragma unroll
      for (int i = 0; i < 4; ++i) {
        const int r = q * 4 + i;
        const u16 hv = f2bf(acc[nt][i] + bias);
        outw[(m0 + r) * 512 + n] = hv;
        x_s[r * 520 + n] = hv;
      }
    }
  }
  __syncthreads();

  // ---- phase B: z chunk 16 x 64 per wave, K = 512 ----
  {
    f32x4 acc[4];
#pragma unroll
    for (int c = 0; c < 4; ++c) acc[c] = (f32x4){0.f, 0.f, 0.f, 0.f};

#pragma unroll 1
    for (int kt = 0; kt < 16; ++kt) {
      bf16x8 afr = __builtin_bit_cast(bf16x8, *(const uint4*)(x_s + c0 * 520 + kt * 32 + q * 8));
      bf16x8 bfr[4];
#pragma unroll
      for (int nt = 0; nt < 4; ++nt)
        bfr[nt] = ld_frag_g(W1tp + ((kt * 16 + w * 4 + nt) * 64 + lane) * 8);
#pragma unroll
      for (int nt = 0; nt < 4; ++nt)
        acc[nt] = __builtin_amdgcn_mfma_f32_16x16x32_bf16(afr, bfr[nt], acc[nt], 0, 0, 0);
    }

#pragma unroll
    for (int nt = 0; nt < 4; ++nt) {
      const int n = (w * 4 + nt) * 16 + c0;
#pragma unroll
      for (int i = 0; i < 4; ++i)
        zbuf[(m0 + q * 4 + i) * 256 + n] = acc[nt][i];   // no bias: b1 already in x
    }
  }
}

// ---------------------------------------------------------------------------
// k_attn: pure fp32, memory-bound. One block (256 thr = 4 waves) per batch b.
//   lane l of wave w holds o[w*16+r, 4l..4l+3] (16 f32x4 regs, NT read ONCE).
//   alpha via log-tree multi-value butterfly: 17 shuffles (was 96).
//   beta = softmax64(alpha);  obar = sum_n beta_n o_n -> bf16 obarb [4096,256]
// ---------------------------------------------------------------------------
__global__ __launch_bounds__(256, 4) void k_attn(const float* __restrict__ others,
                                                 const float* __restrict__ zbuf,
                                                 u16* __restrict__ obarb) {
  __shared__ float s_alpha[64];
  __shared__ float s_beta[64];
  __shared__ float s_part[1024];

  const int tid = threadIdx.x;
  const int b = blockIdx.x;
  const int w = tid >> 6, l = tid & 63;
  const float* src = others + (size_t)b * (NNA * FIN);

  const f32x4 z4 = *(const f32x4*)(zbuf + b * 256 + 4 * l);

  f32x4 o4[16];
#pragma unroll
  for (int r = 0; r < 16; ++r)
    o4[r] = ldnt(src + (w * 16 + r) * 256 + 4 * l);

  // per-lane partial dot for each of this wave's 16 rows
  float v[16];
#pragma unroll
  for (int r = 0; r < 16; ++r)
    v[r] = o4[r][0] * z4[0] + o4[r][1] * z4[1] + o4[r][2] * z4[2] + o4[r][3] * z4[3];

  // log-tree multi-value butterfly: rounds exchange 8,4,2,1 values (masks
  // 1,2,4,8), then 2 full-value rounds (16,32). All reg indices static.
#pragma unroll
  for (int k = 0; k < 4; ++k) {
    const int m = 1 << k;
    const int half = 8 >> k;
    const bool hi = (l & m) != 0;
#pragma unroll
    for (int i = 0; i < half; ++i) {
      float a = v[i], bv = v[i + half];
      float send = hi ? a : bv;
      float keep = hi ? bv : a;
      v[i] = keep + __shfl_xor(send, m);
    }
  }
  v[0] += __shfl_xor(v[0], 16);
  v[0] += __shfl_xor(v[0], 32);
  // lane l (l<16) now holds full alpha of local row rr (bit-reversed l):
  const int rr = ((l & 1) << 3) | (((l >> 1) & 1) << 2) | (((l >> 2) & 1) << 1) | ((l >> 3) & 1);
  if (l < 16) s_alpha[w * 16 + rr] = v[0] * 0.04419417382415922f;  // 1/sqrt(512)
  __syncthreads();

  if (tid < 64) {   // wave 0: softmax over the 64 agents
    float x = s_alpha[tid];
    float mx = x;
#pragma unroll
    for (int off = 1; off < 64; off <<= 1) mx = fmaxf(mx, __shfl_xor(mx, off));
    float e = __expf(x - mx);
    float se = e;
#pragma unroll
    for (int off = 1; off < 64; off <<= 1) se += __shfl_xor(se, off);
    s_beta[tid] = e / se;
  }
  __syncthreads();

  f32x4 p = (f32x4){0.f, 0.f, 0.f, 0.f};
#pragma unroll
  for (int r = 0; r < 16; ++r) {
    const float bb = s_beta[w * 16 + r];
    p[0] += bb * o4[r][0]; p[1] += bb * o4[r][1]; p[2] += bb * o4[r][2]; p[3] += bb * o4[r][3];
  }
  *(f32x4*)(&s_part[w * 256 + 4 * l]) = p;
  __syncthreads();

  const float vv = s_part[tid] + s_part[tid + 256] + s_part[tid + 512] + s_part[tid + 768];
  obarb[(size_t)b * 256 + tid] = f2bf(vv);
}

// ---------------------------------------------------------------------------
// k_tail: fused c + head. Grid 256 x 128 thr (2 waves), 16 rows per block.
// Phase 1: c[16,512] = obar@W1 + b1 (bf16) -> LDS c_s (stride 520).
//          Wave w: 16 rows x cols [w*256, w*256+256), K=256.
// Phase 2: head 16x128 K=1024. A-frags: k<512 from outw (x, global),
//          k>=512 from LDS c_s. Wave w: cols [w*64, w*64+64).
//          Row softmax across the 2 waves via tiny LDS max/sum exchange.
// ---------------------------------------------------------------------------
__global__ __launch_bounds__(128) void k_tail(const u16* __restrict__ outw,
                                              const u16* __restrict__ obarb,
                                              const u16* __restrict__ W1p,
                                              const float* __restrict__ pb1,
                                              const u16* __restrict__ W2p,
                                              const float* __restrict__ pb2,
                                              const int* __restrict__ mask,
                                              float* __restrict__ out) {
  __shared__ __align__(16) u16 c_s[16 * 520];
  __shared__ float s_mx[2][16];
  __shared__ float s_se[2][16];

  const int tid = threadIdx.x;
  const int w = tid >> 6, lane = tid & 63;
  const int q = lane >> 4, c0 = lane & 15;
  const int m0 = blockIdx.x * 16;

  // ---- phase 1: c chunk 16 x 256 per wave ----
  {
    f32x4 acc[16];
#pragma unroll
    for (int c = 0; c < 16; ++c) acc[c] = (f32x4){0.f, 0.f, 0.f, 0.f};

#pragma unroll 1
    for (int kt = 0; kt < 8; ++kt) {
      bf16x8 afr = ld_frag_g(obarb + (m0 + c0) * 256 + kt * 32 + q * 8);
      bf16x8 bfr[16];
#pragma unroll
      for (int nt = 0; nt < 16; ++nt)
        bfr[nt] = ld_frag_g(W1p + ((kt * 32 + w * 16 + nt) * 64 + lane) * 8);
#pragma unroll
      for (int nt = 0; nt < 16; ++nt)
        acc[nt] = __builtin_amdgcn_mfma_f32_16x16x32_bf16(afr, bfr[nt], acc[nt], 0, 0, 0);
    }

#pragma unroll
    for (int nt = 0; nt < 16; ++nt) {
      const int n = w * 256 + nt * 16 + c0;
      const float bias = pb1[n];
#pragma unroll
      for (int i = 0; i < 4; ++i)
        c_s[(q * 4 + i) * 520 + n] = f2bf(acc[nt][i] + bias);
    }
  }
  __syncthreads();

  // ---- phase 2: head 16 x 64 per wave, K = 1024 ----
  f32x4 acc[4];
#pragma unroll
  for (int c = 0; c < 4; ++c) acc[c] = (f32x4){0.f, 0.f, 0.f, 0.f};

#pragma unroll 1
  for (int kt = 0; kt < 16; ++kt) {     // k in [0,512): x from global
    bf16x8 afr = ld_frag_g(outw + (m0 + c0) * 512 + kt * 32 + q * 8);
    bf16x8 bfr[4];
#pragma unroll
    for (int nt = 0; nt < 4; ++nt)
      bfr[nt] = ld_frag_g(W2p + ((kt * 8 + w * 4 + nt) * 64 + lane) * 8);
#pragma unroll
    for (int nt = 0; nt < 4; ++nt)
      acc[nt] = __builtin_amdgcn_mfma_f32_16x16x32_bf16(afr, bfr[nt], acc[nt], 0, 0, 0);
  }
#pragma unroll 1
  for (int kt = 0; kt < 16; ++kt) {     // k in [512,1024): c from LDS
    bf16x8 afr = __builtin_bit_cast(bf16x8, *(const uint4*)(c_s + c0 * 520 + kt * 32 + q * 8));
    bf16x8 bfr[4];
#pragma unroll
    for (int nt = 0; nt < 4; ++nt)
      bfr[nt] = ld_frag_g(W2p + (((kt + 16) * 8 + w * 4 + nt) * 64 + lane) * 8);
#pragma unroll
    for (int nt = 0; nt < 4; ++nt)
      acc[nt] = __builtin_amdgcn_mfma_f32_16x16x32_bf16(afr, bfr[nt], acc[nt], 0, 0, 0);
  }

  float b2f[4];
#pragma unroll
  for (int nt = 0; nt < 4; ++nt) b2f[nt] = pb2[(w * 4 + nt) * 16 + c0];

  float vv[4][4];
  // wave-local row max (over this wave's 64 cols) -> LDS
#pragma unroll
  for (int i = 0; i < 4; ++i) {
    float mx = -3.0e38f;
#pragma unroll
    for (int nt = 0; nt < 4; ++nt) { vv[i][nt] = acc[nt][i] + b2f[nt]; mx = fmaxf(mx, vv[i][nt]); }
    mx = fmaxf(mx, __shfl_xor(mx, 1)); mx = fmaxf(mx, __shfl_xor(mx, 2));
    mx = fmaxf(mx, __shfl_xor(mx, 4)); mx = fmaxf(mx, __shfl_xor(mx, 8));
    if (c0 == 0) s_mx[w][q * 4 + i] = mx;
  }
  __syncthreads();

  // exp with global row max, wave-local sum -> LDS
#pragma unroll
  for (int i = 0; i < 4; ++i) {
    const int r = q * 4 + i;
    const float mx = fmaxf(s_mx[0][r], s_mx[1][r]);
    float se = 0.f;
#pragma unroll
    for (int nt = 0; nt < 4; ++nt) { vv[i][nt] = __expf(vv[i][nt] - mx); se += vv[i][nt]; }
    se += __shfl_xor(se, 1); se += __shfl_xor(se, 2);
    se += __shfl_xor(se, 4); se += __shfl_xor(se, 8);
    if (c0 == 0) s_se[w][q * 4 + i] = se;
  }
  __syncthreads();

#pragma unroll
  for (int i = 0; i < 4; ++i) {
    const int r = q * 4 + i;
    const int row = m0 + r;
    const float inv = 1.f / (s_se[0][r] + s_se[1][r]);
#pragma unroll
    for (int nt = 0; nt < 4; ++nt) {
      const int col = (w * 4 + nt) * 16 + c0;
      float p = fminf(fmaxf(vv[i][nt] * inv, 0.f), 1.f);   // NaN-safe clamp to [0,1]
      float o = mask[row * D2 + col] ? p : (p + NEGV);     // fp32, like the reference
      out[row * D2 + col] = o;
    }
  }
}

extern "C" void kernel_launch(void* const* d_in, const int* in_sizes, int n_in,
                              void* d_out, int out_size, void* d_ws, size_t ws_size,
                              hipStream_t stream) {
  const float* obs = (const float*)d_in[0];   // [4096,256] fp32
  const float* oth = (const float*)d_in[1];   // [4096,64,256] fp32
  const int*   msk = (const int*)d_in[2];     // [4096,128] int32
  const float* W1  = (const float*)d_in[3];   // [256,512] fp32
  const float* b1  = (const float*)d_in[4];   // [512] fp32
  const float* W2  = (const float*)d_in[5];   // [1024,128] fp32
  const float* b2  = (const float*)d_in[6];   // [128] fp32
  // d_in[7..10] = W3,b3,W4,b4: dead code (value head deleted in reference)
  float* out = (float*)d_out;                 // [4096,128] fp32

  char* ws = (char*)d_ws;
  u16*   W1p   = (u16*)ws;                      //   262144 B
  u16*   W2p   = (u16*)(ws + 262144);           //    65536 B
  u16*   W1tp  = (u16*)(ws + 327680);           //   262144 B
  u16*   outw  = (u16*)(ws + 589824);           //  4194304 B  [4096,512] bf16 (x only)
  float* zbuf  = (float*)(ws + 4784128);        //  4194304 B  [4096,256] fp32
  u16*   obarb = (u16*)(ws + 8978432);          //  2097152 B  [4096,256] bf16
                                                // total ~11.1 MB

  k_prep<<<1152, 256, 0, stream>>>(W1, W2, W1p, W2p, W1tp);
  k_xz<<<256, 256, 0, stream>>>(obs, W1p, W1tp, b1, outw, zbuf);
  k_attn<<<4096, 256, 0, stream>>>(oth, zbuf, obarb);
  k_tail<<<256, 128, 0, stream>>>(outw, obarb, W1p, b1, W2p, b2, msk, out);
}

// Round 6
// 389.222 us; speedup vs baseline: 1.2402x; 1.0059x over previous
//
#include <hip/hip_runtime.h>
#include <hip/hip_bf16.h>

// Problem: B=4096, N=64, FIN=256, D1=512, D2=128.
// Algebraic restructuring of the attention (exact, not approximate):
//   alpha[b,n] = o_bn . z_b (+const),  z = x @ W1^T   (softmax shift-invariant)
//   c_b = (sum_n beta_n o_bn) @ W1 + b1               (sum beta = 1)
// Pipeline (4 dispatches): prep -> k_xz (x=obs@W1+b1, z=x@W1^T fused via LDS)
//   -> k_attn (pure fp32 streaming of `others`, log-tree alpha reduce, obar out)
//   -> k_tail (c=obar@W1+b1 in LDS, head GEMM + softmax + mask, fused).
// R5: TLP pass — k_xz 8 waves/block, k_tail 4 waves/block (same 256-block
// grids, narrower per-wave column slices), k_prep vectorized 8 elems/thread.
// R6: identical resubmit (R5 bench was an infra failure, kernel never ran).

typedef unsigned short u16;
typedef __bf16 bf16x8 __attribute__((ext_vector_type(8)));
typedef float f32x4 __attribute__((ext_vector_type(4)));

#define FIN 256
#define D1  512
#define D2  128
#define NNA 64
#define NEGV -10000000.0f

__device__ __forceinline__ float bf2f(u16 u) {
  unsigned int i = ((unsigned int)u) << 16;
  return __builtin_bit_cast(float, i);
}
__device__ __forceinline__ u16 f2bf(float f) {
  unsigned int i = __builtin_bit_cast(unsigned int, f);
  return (u16)((i + 0x7FFFu + ((i >> 16) & 1u)) >> 16);
}
__device__ __forceinline__ bf16x8 ld_frag_g(const u16* p) {   // 16B bf16 fragment
  return __builtin_bit_cast(bf16x8, *(const uint4*)p);
}
// load 8 consecutive fp32, convert to bf16x8 fragment
__device__ __forceinline__ bf16x8 ld_frag_f32(const float* p) {
  float4 a = *(const float4*)p, b = *(const float4*)(p + 4);
  u16 s[8];
  s[0] = f2bf(a.x); s[1] = f2bf(a.y); s[2] = f2bf(a.z); s[3] = f2bf(a.w);
  s[4] = f2bf(b.x); s[5] = f2bf(b.y); s[6] = f2bf(b.z); s[7] = f2bf(b.w);
  return __builtin_bit_cast(bf16x8, *(uint4*)s);
}
// streaming read-once 16B load (ext_vector type: valid for the builtin)
__device__ __forceinline__ f32x4 ldnt(const float* p) {
  return __builtin_nontemporal_load((const f32x4*)p);
}

// ---------------------------------------------------------------------------
// k_prep: W1 [256,512] -> W1p (B-frags, K=256,N=512); W2 [1024,128] -> W2p
// (K=1024,N=128); W1^T [512,256] -> W1tp (B-frags, K=512,N=256).
// Frag layout: P[((kt*NT + nt)*64 + lane)*8 + j] = M[kt*32+(lane>>4)*8+j][nt*16+(lane&15)]
// 8 bf16 per thread (one uint4 store). c-space: [0,16384) W1p, [16384,20480)
// W2p, [20480,36864) W1tp. 144 blocks x 256 thr.
// ---------------------------------------------------------------------------
__global__ __launch_bounds__(256) void k_prep(const float* __restrict__ W1,
                                              const float* __restrict__ W2,
                                              u16* __restrict__ W1p,
                                              u16* __restrict__ W2p,
                                              u16* __restrict__ W1tp) {
  int c = blockIdx.x * 256 + threadIdx.x;
  u16 s[8];
  if (c < 16384) {                       // W1p
    int lane = c & 63, nt = (c >> 6) & 31, kt = c >> 11;
    int kb = kt * 32 + (lane >> 4) * 8;
    int n = nt * 16 + (lane & 15);
#pragma unroll
    for (int j = 0; j < 8; ++j) s[j] = f2bf(W1[(kb + j) * D1 + n]);
    *(uint4*)(W1p + c * 8) = *(uint4*)s;
  } else if (c < 20480) {                // W2p
    int cl = c - 16384;
    int lane = cl & 63, nt = (cl >> 6) & 7, kt = cl >> 9;
    int kb = kt * 32 + (lane >> 4) * 8;
    int n = nt * 16 + (lane & 15);
#pragma unroll
    for (int j = 0; j < 8; ++j) s[j] = f2bf(W2[(kb + j) * D2 + n]);
    *(uint4*)(W2p + cl * 8) = *(uint4*)s;
  } else {                               // W1tp: W1^T[k][n] = W1[n][k]
    int cl = c - 20480;
    int lane = cl & 63, nt = (cl >> 6) & 15, kt = cl >> 10;
    int kb = kt * 32 + (lane >> 4) * 8;
    int n = nt * 16 + (lane & 15);
    float4 a = *(const float4*)(W1 + n * D1 + kb);
    float4 b = *(const float4*)(W1 + n * D1 + kb + 4);
    s[0] = f2bf(a.x); s[1] = f2bf(a.y); s[2] = f2bf(a.z); s[3] = f2bf(a.w);
    s[4] = f2bf(b.x); s[5] = f2bf(b.y); s[6] = f2bf(b.z); s[7] = f2bf(b.w);
    *(uint4*)(W1tp + cl * 8) = *(uint4*)s;
  }
}

// ---------------------------------------------------------------------------
// k_xz: fused x + z. Grid 256 x 512 thr (8 waves), 16 rows per block.
// Phase A: x[16,512] = obs@W1 + b1; wave w -> cols [w*64, w*64+64), K=256.
//          bf16 x written to global outw AND to LDS x_s (stride 520).
// Phase B: z[16,256] = x@W1^T (K=512); wave w -> cols [w*32, w*32+32).
//          A-frags from LDS (same bf16 values => numerics identical).
// ---------------------------------------------------------------------------
__global__ __launch_bounds__(512) void k_xz(const float* __restrict__ obs,
                                            const u16* __restrict__ W1p,
                                            const u16* __restrict__ W1tp,
                                            const float* __restrict__ pb1,
                                            u16* __restrict__ outw,
                                            float* __restrict__ zbuf) {
  __shared__ __align__(16) u16 x_s[16 * 520];

  const int tid = threadIdx.x;
  const int w = tid >> 6, lane = tid & 63;
  const int q = lane >> 4, c0 = lane & 15;
  const int m0 = blockIdx.x * 16;

  // ---- phase A: x chunk 16 x 64 per wave (4 col-tiles) ----
  {
    f32x4 acc[4];
#pragma unroll
    for (int c = 0; c < 4; ++c) acc[c] = (f32x4){0.f, 0.f, 0.f, 0.f};

#pragma unroll 1
    for (int kt = 0; kt < 8; ++kt) {
      bf16x8 afr = ld_frag_f32(obs + (m0 + c0) * FIN + kt * 32 + q * 8);
      bf16x8 bfr[4];
#pragma unroll
      for (int nt = 0; nt < 4; ++nt)
        bfr[nt] = ld_frag_g(W1p + ((kt * 32 + w * 4 + nt) * 64 + lane) * 8);
#pragma unroll
      for (int nt = 0; nt < 4; ++nt)
        acc[nt] = __builtin_amdgcn_mfma_f32_16x16x32_bf16(afr, bfr[nt], acc[nt], 0, 0, 0);
    }

#pragma unroll
    for (int nt = 0; nt < 4; ++nt) {
      const int n = (w * 4 + nt) * 16 + c0;
      const float bias = pb1[n];
#pragma unroll
      for (int i = 0; i < 4; ++i) {
        const int r = q * 4 + i;
        const u16 hv = f2bf(acc[nt][i] + bias);
        outw[(m0 + r) * 512 + n] = hv;
        x_s[r * 520 + n] = hv;
      }
    }
  }
  __syncthreads();

  // ---- phase B: z chunk 16 x 32 per wave (2 col-tiles), K = 512 ----
  {
    f32x4 acc[2];
#pragma unroll
    for (int c = 0; c < 2; ++c) acc[c] = (f32x4){0.f, 0.f, 0.f, 0.f};

#pragma unroll 1
    for (int kt = 0; kt < 16; ++kt) {
      bf16x8 afr = __builtin_bit_cast(bf16x8, *(const uint4*)(x_s + c0 * 520 + kt * 32 + q * 8));
      bf16x8 bfr[2];
#pragma unroll
      for (int nt = 0; nt < 2; ++nt)
        bfr[nt] = ld_frag_g(W1tp + ((kt * 16 + w * 2 + nt) * 64 + lane) * 8);
#pragma unroll
      for (int nt = 0; nt < 2; ++nt)
        acc[nt] = __builtin_amdgcn_mfma_f32_16x16x32_bf16(afr, bfr[nt], acc[nt], 0, 0, 0);
    }

#pragma unroll
    for (int nt = 0; nt < 2; ++nt) {
      const int n = (w * 2 + nt) * 16 + c0;
#pragma unroll
      for (int i = 0; i < 4; ++i)
        zbuf[(m0 + q * 4 + i) * 256 + n] = acc[nt][i];   // no bias: b1 already in x
    }
  }
}

// ---------------------------------------------------------------------------
// k_attn: pure fp32, memory-bound. One block (256 thr = 4 waves) per batch b.
//   lane l of wave w holds o[w*16+r, 4l..4l+3] (16 f32x4 regs, NT read ONCE).
//   alpha via log-tree multi-value butterfly: 17 shuffles.
//   beta = softmax64(alpha);  obar = sum_n beta_n o_n -> bf16 obarb [4096,256]
// ---------------------------------------------------------------------------
__global__ __launch_bounds__(256, 4) void k_attn(const float* __restrict__ others,
                                                 const float* __restrict__ zbuf,
                                                 u16* __restrict__ obarb) {
  __shared__ float s_alpha[64];
  __shared__ float s_beta[64];
  __shared__ float s_part[1024];

  const int tid = threadIdx.x;
  const int b = blockIdx.x;
  const int w = tid >> 6, l = tid & 63;
  const float* src = others + (size_t)b * (NNA * FIN);

  const f32x4 z4 = *(const f32x4*)(zbuf + b * 256 + 4 * l);

  f32x4 o4[16];
#pragma unroll
  for (int r = 0; r < 16; ++r)
    o4[r] = ldnt(src + (w * 16 + r) * 256 + 4 * l);

  // per-lane partial dot for each of this wave's 16 rows
  float v[16];
#pragma unroll
  for (int r = 0; r < 16; ++r)
    v[r] = o4[r][0] * z4[0] + o4[r][1] * z4[1] + o4[r][2] * z4[2] + o4[r][3] * z4[3];

  // log-tree multi-value butterfly: rounds exchange 8,4,2,1 values (masks
  // 1,2,4,8), then 2 full-value rounds (16,32). All reg indices static.
#pragma unroll
  for (int k = 0; k < 4; ++k) {
    const int m = 1 << k;
    const int half = 8 >> k;
    const bool hi = (l & m) != 0;
#pragma unroll
    for (int i = 0; i < half; ++i) {
      float a = v[i], bv = v[i + half];
      float send = hi ? a : bv;
      float keep = hi ? bv : a;
      v[i] = keep + __shfl_xor(send, m);
    }
  }
  v[0] += __shfl_xor(v[0], 16);
  v[0] += __shfl_xor(v[0], 32);
  // lane l (l<16) now holds full alpha of local row rr (bit-reversed l):
  const int rr = ((l & 1) << 3) | (((l >> 1) & 1) << 2) | (((l >> 2) & 1) << 1) | ((l >> 3) & 1);
  if (l < 16) s_alpha[w * 16 + rr] = v[0] * 0.04419417382415922f;  // 1/sqrt(512)
  __syncthreads();

  if (tid < 64) {   // wave 0: softmax over the 64 agents
    float x = s_alpha[tid];
    float mx = x;
#pragma unroll
    for (int off = 1; off < 64; off <<= 1) mx = fmaxf(mx, __shfl_xor(mx, off));
    float e = __expf(x - mx);
    float se = e;
#pragma unroll
    for (int off = 1; off < 64; off <<= 1) se += __shfl_xor(se, off);
    s_beta[tid] = e / se;
  }
  __syncthreads();

  f32x4 p = (f32x4){0.f, 0.f, 0.f, 0.f};
#pragma unroll
  for (int r = 0; r < 16; ++r) {
    const float bb = s_beta[w * 16 + r];
    p[0] += bb * o4[r][0]; p[1] += bb * o4[r][1]; p[2] += bb * o4[r][2]; p[3] += bb * o4[r][3];
  }
  *(f32x4*)(&s_part[w * 256 + 4 * l]) = p;
  __syncthreads();

  const float vv = s_part[tid] + s_part[tid + 256] + s_part[tid + 512] + s_part[tid + 768];
  obarb[(size_t)b * 256 + tid] = f2bf(vv);
}

// ---------------------------------------------------------------------------
// k_tail: fused c + head. Grid 256 x 256 thr (4 waves), 16 rows per block.
// Phase 1: c[16,512] = obar@W1 + b1 (bf16) -> LDS c_s (stride 520).
//          Wave w: 16 rows x cols [w*128, w*128+128), K=256.
// Phase 2: head 16x128 K=1024. A-frags: k<512 from outw (x, global),
//          k>=512 from LDS c_s. Wave w: cols [w*32, w*32+32).
//          Row softmax across the 4 waves via tiny LDS max/sum exchange.
// ---------------------------------------------------------------------------
__global__ __launch_bounds__(256) void k_tail(const u16* __restrict__ outw,
                                              const u16* __restrict__ obarb,
                                              const u16* __restrict__ W1p,
                                              const float* __restrict__ pb1,
                                              const u16* __restrict__ W2p,
                                              const float* __restrict__ pb2,
                                              const int* __restrict__ mask,
                                              float* __restrict__ out) {
  __shared__ __align__(16) u16 c_s[16 * 520];
  __shared__ float s_mx[4][16];
  __shared__ float s_se[4][16];

  const int tid = threadIdx.x;
  const int w = tid >> 6, lane = tid & 63;
  const int q = lane >> 4, c0 = lane & 15;
  const int m0 = blockIdx.x * 16;

  // ---- phase 1: c chunk 16 x 128 per wave (8 col-tiles) ----
  {
    f32x4 acc[8];
#pragma unroll
    for (int c = 0; c < 8; ++c) acc[c] = (f32x4){0.f, 0.f, 0.f, 0.f};

#pragma unroll 1
    for (int kt = 0; kt < 8; ++kt) {
      bf16x8 afr = ld_frag_g(obarb + (m0 + c0) * 256 + kt * 32 + q * 8);
      bf16x8 bfr[8];
#pragma unroll
      for (int nt = 0; nt < 8; ++nt)
        bfr[nt] = ld_frag_g(W1p + ((kt * 32 + w * 8 + nt) * 64 + lane) * 8);
#pragma unroll
      for (int nt = 0; nt < 8; ++nt)
        acc[nt] = __builtin_amdgcn_mfma_f32_16x16x32_bf16(afr, bfr[nt], acc[nt], 0, 0, 0);
    }

#pragma unroll
    for (int nt = 0; nt < 8; ++nt) {
      const int n = (w * 8 + nt) * 16 + c0;
      const float bias = pb1[n];
#pragma unroll
      for (int i = 0; i < 4; ++i)
        c_s[(q * 4 + i) * 520 + n] = f2bf(acc[nt][i] + bias);
    }
  }
  __syncthreads();

  // ---- phase 2: head 16 x 32 per wave (2 col-tiles), K = 1024 ----
  f32x4 acc[2];
#pragma unroll
  for (int c = 0; c < 2; ++c) acc[c] = (f32x4){0.f, 0.f, 0.f, 0.f};

#pragma unroll 1
  for (int kt = 0; kt < 16; ++kt) {     // k in [0,512): x from global
    bf16x8 afr = ld_frag_g(outw + (m0 + c0) * 512 + kt * 32 + q * 8);
    bf16x8 bfr[2];
#pragma unroll
    for (int nt = 0; nt < 2; ++nt)
      bfr[nt] = ld_frag_g(W2p + ((kt * 8 + w * 2 + nt) * 64 + lane) * 8);
#pragma unroll
    for (int nt = 0; nt < 2; ++nt)
      acc[nt] = __builtin_amdgcn_mfma_f32_16x16x32_bf16(afr, bfr[nt], acc[nt], 0, 0, 0);
  }
#pragma unroll 1
  for (int kt = 0; kt < 16; ++kt) {     // k in [512,1024): c from LDS
    bf16x8 afr = __builtin_bit_cast(bf16x8, *(const uint4*)(c_s + c0 * 520 + kt * 32 + q * 8));
    bf16x8 bfr[2];
#pragma unroll
    for (int nt = 0; nt < 2; ++nt)
      bfr[nt] = ld_frag_g(W2p + (((kt + 16) * 8 + w * 2 + nt) * 64 + lane) * 8);
#pragma unroll
    for (int nt = 0; nt < 2; ++nt)
      acc[nt] = __builtin_amdgcn_mfma_f32_16x16x32_bf16(afr, bfr[nt], acc[nt], 0, 0, 0);
  }

  float b2f[2];
#pragma unroll
  for (int nt = 0; nt < 2; ++nt) b2f[nt] = pb2[(w * 2 + nt) * 16 + c0];

  float vv[4][2];
  // wave-local row max (over this wave's 32 cols) -> LDS
#pragma unroll
  for (int i = 0; i < 4; ++i) {
    float mx = -3.0e38f;
#pragma unroll
    for (int nt = 0; nt < 2; ++nt) { vv[i][nt] = acc[nt][i] + b2f[nt]; mx = fmaxf(mx, vv[i][nt]); }
    mx = fmaxf(mx, __shfl_xor(mx, 1)); mx = fmaxf(mx, __shfl_xor(mx, 2));
    mx = fmaxf(mx, __shfl_xor(mx, 4)); mx = fmaxf(mx, __shfl_xor(mx, 8));
    if (c0 == 0) s_mx[w][q * 4 + i] = mx;
  }
  __syncthreads();

  // exp with global row max, wave-local sum -> LDS
#pragma unroll
  for (int i = 0; i < 4; ++i) {
    const int r = q * 4 + i;
    const float mx = fmaxf(fmaxf(s_mx[0][r], s_mx[1][r]), fmaxf(s_mx[2][r], s_mx[3][r]));
    float se = 0.f;
#pragma unroll
    for (int nt = 0; nt < 2; ++nt) { vv[i][nt] = __expf(vv[i][nt] - mx); se += vv[i][nt]; }
    se += __shfl_xor(se, 1); se += __shfl_xor(se, 2);
    se += __shfl_xor(se, 4); se += __shfl_xor(se, 8);
    if (c0 == 0) s_se[w][q * 4 + i] = se;
  }
  __syncthreads();

#pragma unroll
  for (int i = 0; i < 4; ++i) {
    const int r = q * 4 + i;
    const int row = m0 + r;
    const float inv = 1.f / (s_se[0][r] + s_se[1][r] + s_se[2][r] + s_se[3][r]);
#pragma unroll
    for (int nt = 0; nt < 2; ++nt) {
      const int col = (w * 2 + nt) * 16 + c0;
      float p = fminf(fmaxf(vv[i][nt] * inv, 0.f), 1.f);   // NaN-safe clamp to [0,1]
      float o = mask[row * D2 + col] ? p : (p + NEGV);     // fp32, like the reference
      out[row * D2 + col] = o;
    }
  }
}

extern "C" void kernel_launch(void* const* d_in, const int* in_sizes, int n_in,
                              void* d_out, int out_size, void* d_ws, size_t ws_size,
                              hipStream_t stream) {
  const float* obs = (const float*)d_in[0];   // [4096,256] fp32
  const float* oth = (const float*)d_in[1];   // [4096,64,256] fp32
  const int*   msk = (const int*)d_in[2];     // [4096,128] int32
  const float* W1  = (const float*)d_in[3];   // [256,512] fp32
  const float* b1  = (const float*)d_in[4];   // [512] fp32
  const float* W2  = (const float*)d_in[5];   // [1024,128] fp32
  const float* b2  = (const float*)d_in[6];   // [128] fp32
  // d_in[7..10] = W3,b3,W4,b4: dead code (value head deleted in reference)
  float* out = (float*)d_out;                 // [4096,128] fp32

  char* ws = (char*)d_ws;
  u16*   W1p   = (u16*)ws;                      //   262144 B
  u16*   W2p   = (u16*)(ws + 262144);           //    65536 B
  u16*   W1tp  = (u16*)(ws + 327680);           //   262144 B
  u16*   outw  = (u16*)(ws + 589824);           //  4194304 B  [4096,512] bf16 (x only)
  float* zbuf  = (float*)(ws + 4784128);        //  4194304 B  [4096,256] fp32
  u16*   obarb = (u16*)(ws + 8978432);          //  2097152 B  [4096,256] bf16
                                                // total ~11.1 MB

  k_prep<<<144, 256, 0, stream>>>(W1, W2, W1p, W2p, W1tp);
  k_xz<<<256, 512, 0, stream>>>(obs, W1p, W1tp, b1, outw, zbuf);
  k_attn<<<4096, 256, 0, stream>>>(oth, zbuf, obarb);
  k_tail<<<256, 256, 0, stream>>>(outw, obarb, W1p, b1, W2p, b2, msk, out);
}

// Round 7
// 384.825 us; speedup vs baseline: 1.2544x; 1.0114x over previous
//
#include <hip/hip_runtime.h>
#include <hip/hip_bf16.h>

// Problem: B=4096, N=64, FIN=256, D1=512, D2=128.
// Algebraic restructuring (exact): alpha = o.z (z = x@W1^T, softmax shift-inv),
// c = (sum beta o)@W1 + b1. R7: GRAND FUSION — one kernel per 16 batch rows:
//   phase X: x[16,512]=obs@W1+b1 -> LDS
//   phase Z: z[16,256]=x@W1^T    -> LDS (aliased with c)
//   phase ATT: 16x cooperative attention (4 waves x 16 agents), obar -> LDS
//   phase C: c[16,512]=obar@W1+b1 -> LDS
//   phase HEAD: softmax(out@W2+b2)+mask -> global
// 2 dispatches total (prep, all); no intermediate global traffic.

typedef unsigned short u16;
typedef __bf16 bf16x8 __attribute__((ext_vector_type(8)));
typedef float f32x4 __attribute__((ext_vector_type(4)));

#define FIN 256
#define D1  512
#define D2  128
#define NNA 64
#define NEGV -10000000.0f

__device__ __forceinline__ float bf2f(u16 u) {
  unsigned int i = ((unsigned int)u) << 16;
  return __builtin_bit_cast(float, i);
}
__device__ __forceinline__ u16 f2bf(float f) {
  unsigned int i = __builtin_bit_cast(unsigned int, f);
  return (u16)((i + 0x7FFFu + ((i >> 16) & 1u)) >> 16);
}
__device__ __forceinline__ bf16x8 ld_frag_g(const u16* p) {   // 16B bf16 fragment
  return __builtin_bit_cast(bf16x8, *(const uint4*)p);
}
__device__ __forceinline__ bf16x8 ld_frag_f32(const float* p) {
  float4 a = *(const float4*)p, b = *(const float4*)(p + 4);
  u16 s[8];
  s[0] = f2bf(a.x); s[1] = f2bf(a.y); s[2] = f2bf(a.z); s[3] = f2bf(a.w);
  s[4] = f2bf(b.x); s[5] = f2bf(b.y); s[6] = f2bf(b.z); s[7] = f2bf(b.w);
  return __builtin_bit_cast(bf16x8, *(uint4*)s);
}
__device__ __forceinline__ f32x4 ldnt(const float* p) {       // streaming read-once
  return __builtin_nontemporal_load((const f32x4*)p);
}

// ---------------------------------------------------------------------------
// k_prep: W1 -> W1p (K=256,N=512); W2 -> W2p (K=1024,N=128); W1^T -> W1tp
// (K=512,N=256). Frag layout:
// P[((kt*NT+nt)*64+lane)*8+j] = M[kt*32+(lane>>4)*8+j][nt*16+(lane&15)]
// 8 bf16/thread (uint4 store). 144 blocks x 256 thr.
// ---------------------------------------------------------------------------
__global__ __launch_bounds__(256) void k_prep(const float* __restrict__ W1,
                                              const float* __restrict__ W2,
                                              u16* __restrict__ W1p,
                                              u16* __restrict__ W2p,
                                              u16* __restrict__ W1tp) {
  int c = blockIdx.x * 256 + threadIdx.x;
  u16 s[8];
  if (c < 16384) {                       // W1p
    int lane = c & 63, nt = (c >> 6) & 31, kt = c >> 11;
    int kb = kt * 32 + (lane >> 4) * 8;
    int n = nt * 16 + (lane & 15);
#pragma unroll
    for (int j = 0; j < 8; ++j) s[j] = f2bf(W1[(kb + j) * D1 + n]);
    *(uint4*)(W1p + c * 8) = *(uint4*)s;
  } else if (c < 20480) {                // W2p
    int cl = c - 16384;
    int lane = cl & 63, nt = (cl >> 6) & 7, kt = cl >> 9;
    int kb = kt * 32 + (lane >> 4) * 8;
    int n = nt * 16 + (lane & 15);
#pragma unroll
    for (int j = 0; j < 8; ++j) s[j] = f2bf(W2[(kb + j) * D2 + n]);
    *(uint4*)(W2p + cl * 8) = *(uint4*)s;
  } else {                               // W1tp: W1^T[k][n] = W1[n][k]
    int cl = c - 20480;
    int lane = cl & 63, nt = (cl >> 6) & 15, kt = cl >> 10;
    int kb = kt * 32 + (lane >> 4) * 8;
    int n = nt * 16 + (lane & 15);
    float4 a = *(const float4*)(W1 + n * D1 + kb);
    float4 b = *(const float4*)(W1 + n * D1 + kb + 4);
    s[0] = f2bf(a.x); s[1] = f2bf(a.y); s[2] = f2bf(a.z); s[3] = f2bf(a.w);
    s[4] = f2bf(b.x); s[5] = f2bf(b.y); s[6] = f2bf(b.z); s[7] = f2bf(b.w);
    *(uint4*)(W1tp + cl * 8) = *(uint4*)s;
  }
}

// ---------------------------------------------------------------------------
// k_all: the whole forward for 16 batch rows per block. 256 thr = 4 waves.
// LDS pool (~46.8 KB -> 3 blocks/CU):
//   x_s   [16][520] bf16  (lives X -> HEAD)
//   zc    z[16][256] f32 aliased with c[16][520] bf16 (disjoint lifetimes)
//   obar_s[16][264] bf16  (ATT -> C)
//   s_alpha[64] s_beta[64] s_part[1024] s_mx[4][16] s_se[4][16]
// ---------------------------------------------------------------------------
__global__ __launch_bounds__(256) void k_all(const float* __restrict__ obs,
                                             const float* __restrict__ others,
                                             const u16* __restrict__ W1p,
                                             const u16* __restrict__ W1tp,
                                             const u16* __restrict__ W2p,
                                             const float* __restrict__ pb1,
                                             const float* __restrict__ pb2,
                                             const int* __restrict__ mask,
                                             float* __restrict__ out) {
  __shared__ __align__(16) char pool[46848];
  u16*   x_s     = (u16*)pool;                    // 16640 B
  float* z_s     = (float*)(pool + 16640);        // 16384 B (alias c_s)
  u16*   c_s     = (u16*)(pool + 16640);          // 16640 B (alias z_s)
  u16*   obar_s  = (u16*)(pool + 33280);          //  8448 B
  float* s_alpha = (float*)(pool + 41728);        //   256 B
  float* s_beta  = (float*)(pool + 41984);        //   256 B
  float* s_part  = (float*)(pool + 42240);        //  4096 B
  float* s_mx    = (float*)(pool + 46336);        //   256 B  [4][16]
  float* s_se    = (float*)(pool + 46592);        //   256 B  [4][16]

  const int tid = threadIdx.x;
  const int w = tid >> 6, lane = tid & 63;
  const int q = lane >> 4, c0 = lane & 15;
  const int m0 = blockIdx.x * 16;

  // ---- phase X: x[16,512] = obs@W1 + b1 -> x_s. wave w: cols [w*128,...) ----
  {
    f32x4 acc[8];
#pragma unroll
    for (int c = 0; c < 8; ++c) acc[c] = (f32x4){0.f, 0.f, 0.f, 0.f};

#pragma unroll 1
    for (int kt = 0; kt < 8; ++kt) {
      bf16x8 afr = ld_frag_f32(obs + (m0 + c0) * FIN + kt * 32 + q * 8);
      bf16x8 bfr[8];
#pragma unroll
      for (int nt = 0; nt < 8; ++nt)
        bfr[nt] = ld_frag_g(W1p + ((kt * 32 + w * 8 + nt) * 64 + lane) * 8);
#pragma unroll
      for (int nt = 0; nt < 8; ++nt)
        acc[nt] = __builtin_amdgcn_mfma_f32_16x16x32_bf16(afr, bfr[nt], acc[nt], 0, 0, 0);
    }

#pragma unroll
    for (int nt = 0; nt < 8; ++nt) {
      const int n = (w * 8 + nt) * 16 + c0;
      const float bias = pb1[n];
#pragma unroll
      for (int i = 0; i < 4; ++i)
        x_s[(q * 4 + i) * 520 + n] = f2bf(acc[nt][i] + bias);
    }
  }
  __syncthreads();

  // ---- phase Z: z[16,256] = x@W1^T (K=512) -> z_s. wave w: cols [w*64,...) ----
  {
    f32x4 acc[4];
#pragma unroll
    for (int c = 0; c < 4; ++c) acc[c] = (f32x4){0.f, 0.f, 0.f, 0.f};

#pragma unroll 1
    for (int kt = 0; kt < 16; ++kt) {
      bf16x8 afr = __builtin_bit_cast(bf16x8, *(const uint4*)(x_s + c0 * 520 + kt * 32 + q * 8));
      bf16x8 bfr[4];
#pragma unroll
      for (int nt = 0; nt < 4; ++nt)
        bfr[nt] = ld_frag_g(W1tp + ((kt * 16 + w * 4 + nt) * 64 + lane) * 8);
#pragma unroll
      for (int nt = 0; nt < 4; ++nt)
        acc[nt] = __builtin_amdgcn_mfma_f32_16x16x32_bf16(afr, bfr[nt], acc[nt], 0, 0, 0);
    }

#pragma unroll
    for (int nt = 0; nt < 4; ++nt) {
      const int n = (w * 4 + nt) * 16 + c0;
#pragma unroll
      for (int i = 0; i < 4; ++i)
        z_s[(q * 4 + i) * 256 + n] = acc[nt][i];   // no bias: b1 already in x
    }
  }
  __syncthreads();

  // ---- phase ATT: 16 batches, block-cooperative (verbatim R6 structure) ----
#pragma unroll 1
  for (int bi = 0; bi < 16; ++bi) {
    const float* src = others + (size_t)(m0 + bi) * (NNA * FIN);
    const f32x4 z4 = *(const f32x4*)(z_s + bi * 256 + 4 * lane);

    f32x4 o4[16];
#pragma unroll
    for (int r = 0; r < 16; ++r)
      o4[r] = ldnt(src + (w * 16 + r) * 256 + 4 * lane);

    float v[16];
#pragma unroll
    for (int r = 0; r < 16; ++r)
      v[r] = o4[r][0] * z4[0] + o4[r][1] * z4[1] + o4[r][2] * z4[2] + o4[r][3] * z4[3];

    // log-tree multi-value butterfly: 4 rounds (masks 1,2,4,8) + 2 full rounds
#pragma unroll
    for (int k = 0; k < 4; ++k) {
      const int m = 1 << k;
      const int half = 8 >> k;
      const bool hi = (lane & m) != 0;
#pragma unroll
      for (int i = 0; i < half; ++i) {
        float a = v[i], bv = v[i + half];
        float send = hi ? a : bv;
        float keep = hi ? bv : a;
        v[i] = keep + __shfl_xor(send, m);
      }
    }
    v[0] += __shfl_xor(v[0], 16);
    v[0] += __shfl_xor(v[0], 32);
    const int rr = ((lane & 1) << 3) | (((lane >> 1) & 1) << 2) |
                   (((lane >> 2) & 1) << 1) | ((lane >> 3) & 1);
    if (lane < 16) s_alpha[w * 16 + rr] = v[0] * 0.04419417382415922f;  // 1/sqrt(512)
    __syncthreads();

    if (tid < 64) {   // wave 0: softmax over the 64 agents
      float x = s_alpha[tid];
      float mx = x;
#pragma unroll
      for (int off = 1; off < 64; off <<= 1) mx = fmaxf(mx, __shfl_xor(mx, off));
      float e = __expf(x - mx);
      float se = e;
#pragma unroll
      for (int off = 1; off < 64; off <<= 1) se += __shfl_xor(se, off);
      s_beta[tid] = e / se;
    }
    __syncthreads();

    f32x4 p = (f32x4){0.f, 0.f, 0.f, 0.f};
#pragma unroll
    for (int r = 0; r < 16; ++r) {
      const float bb = s_beta[w * 16 + r];
      p[0] += bb * o4[r][0]; p[1] += bb * o4[r][1];
      p[2] += bb * o4[r][2]; p[3] += bb * o4[r][3];
    }
    *(f32x4*)(&s_part[w * 256 + 4 * lane]) = p;
    __syncthreads();

    const float vv = s_part[tid] + s_part[tid + 256] + s_part[tid + 512] + s_part[tid + 768];
    obar_s[bi * 264 + tid] = f2bf(vv);
  }
  __syncthreads();   // obar_s complete; z_s dead -> c_s may overwrite

  // ---- phase C: c[16,512] = obar@W1 + b1 -> c_s. wave w: cols [w*128,...) ----
  {
    f32x4 acc[8];
#pragma unroll
    for (int c = 0; c < 8; ++c) acc[c] = (f32x4){0.f, 0.f, 0.f, 0.f};

#pragma unroll 1
    for (int kt = 0; kt < 8; ++kt) {
      bf16x8 afr = __builtin_bit_cast(bf16x8, *(const uint4*)(obar_s + c0 * 264 + kt * 32 + q * 8));
      bf16x8 bfr[8];
#pragma unroll
      for (int nt = 0; nt < 8; ++nt)
        bfr[nt] = ld_frag_g(W1p + ((kt * 32 + w * 8 + nt) * 64 + lane) * 8);
#pragma unroll
      for (int nt = 0; nt < 8; ++nt)
        acc[nt] = __builtin_amdgcn_mfma_f32_16x16x32_bf16(afr, bfr[nt], acc[nt], 0, 0, 0);
    }

#pragma unroll
    for (int nt = 0; nt < 8; ++nt) {
      const int n = (w * 8 + nt) * 16 + c0;
      const float bias = pb1[n];
#pragma unroll
      for (int i = 0; i < 4; ++i)
        c_s[(q * 4 + i) * 520 + n] = f2bf(acc[nt][i] + bias);
    }
  }
  __syncthreads();

  // ---- phase HEAD: 16x128, K=1024 (x from x_s, c from c_s). wave w: cols [w*32,...) ----
  f32x4 acc[2];
#pragma unroll
  for (int c = 0; c < 2; ++c) acc[c] = (f32x4){0.f, 0.f, 0.f, 0.f};

#pragma unroll 1
  for (int kt = 0; kt < 16; ++kt) {     // k in [0,512): x
    bf16x8 afr = __builtin_bit_cast(bf16x8, *(const uint4*)(x_s + c0 * 520 + kt * 32 + q * 8));
    bf16x8 bfr[2];
#pragma unroll
    for (int nt = 0; nt < 2; ++nt)
      bfr[nt] = ld_frag_g(W2p + ((kt * 8 + w * 2 + nt) * 64 + lane) * 8);
#pragma unroll
    for (int nt = 0; nt < 2; ++nt)
      acc[nt] = __builtin_amdgcn_mfma_f32_16x16x32_bf16(afr, bfr[nt], acc[nt], 0, 0, 0);
  }
#pragma unroll 1
  for (int kt = 0; kt < 16; ++kt) {     // k in [512,1024): c
    bf16x8 afr = __builtin_bit_cast(bf16x8, *(const uint4*)(c_s + c0 * 520 + kt * 32 + q * 8));
    bf16x8 bfr[2];
#pragma unroll
    for (int nt = 0; nt < 2; ++nt)
      bfr[nt] = ld_frag_g(W2p + (((kt + 16) * 8 + w * 2 + nt) * 64 + lane) * 8);
#pragma unroll
    for (int nt = 0; nt < 2; ++nt)
      acc[nt] = __builtin_amdgcn_mfma_f32_16x16x32_bf16(afr, bfr[nt], acc[nt], 0, 0, 0);
  }

  float b2f[2];
#pragma unroll
  for (int nt = 0; nt < 2; ++nt) b2f[nt] = pb2[(w * 2 + nt) * 16 + c0];

  float vv[4][2];
#pragma unroll
  for (int i = 0; i < 4; ++i) {
    float mx = -3.0e38f;
#pragma unroll
    for (int nt = 0; nt < 2; ++nt) { vv[i][nt] = acc[nt][i] + b2f[nt]; mx = fmaxf(mx, vv[i][nt]); }
    mx = fmaxf(mx, __shfl_xor(mx, 1)); mx = fmaxf(mx, __shfl_xor(mx, 2));
    mx = fmaxf(mx, __shfl_xor(mx, 4)); mx = fmaxf(mx, __shfl_xor(mx, 8));
    if (c0 == 0) s_mx[w * 16 + q * 4 + i] = mx;
  }
  __syncthreads();

#pragma unroll
  for (int i = 0; i < 4; ++i) {
    const int r = q * 4 + i;
    const float mx = fmaxf(fmaxf(s_mx[r], s_mx[16 + r]), fmaxf(s_mx[32 + r], s_mx[48 + r]));
    float se = 0.f;
#pragma unroll
    for (int nt = 0; nt < 2; ++nt) { vv[i][nt] = __expf(vv[i][nt] - mx); se += vv[i][nt]; }
    se += __shfl_xor(se, 1); se += __shfl_xor(se, 2);
    se += __shfl_xor(se, 4); se += __shfl_xor(se, 8);
    if (c0 == 0) s_se[w * 16 + q * 4 + i] = se;
  }
  __syncthreads();

#pragma unroll
  for (int i = 0; i < 4; ++i) {
    const int r = q * 4 + i;
    const int row = m0 + r;
    const float inv = 1.f / (s_se[r] + s_se[16 + r] + s_se[32 + r] + s_se[48 + r]);
#pragma unroll
    for (int nt = 0; nt < 2; ++nt) {
      const int col = (w * 2 + nt) * 16 + c0;
      float p = fminf(fmaxf(vv[i][nt] * inv, 0.f), 1.f);   // NaN-safe clamp to [0,1]
      float o = mask[row * D2 + col] ? p : (p + NEGV);     // fp32, like the reference
      out[row * D2 + col] = o;
    }
  }
}

extern "C" void kernel_launch(void* const* d_in, const int* in_sizes, int n_in,
                              void* d_out, int out_size, void* d_ws, size_t ws_size,
                              hipStream_t stream) {
  const float* obs = (const float*)d_in[0];   // [4096,256] fp32
  const float* oth = (const float*)d_in[1];   // [4096,64,256] fp32
  const int*   msk = (const int*)d_in[2];     // [4096,128] int32
  const float* W1  = (const float*)d_in[3];   // [256,512] fp32
  const float* b1  = (const float*)d_in[4];   // [512] fp32
  const float* W2  = (const float*)d_in[5];   // [1024,128] fp32
  const float* b2  = (const float*)d_in[6];   // [128] fp32
  // d_in[7..10] = W3,b3,W4,b4: dead code (value head deleted in reference)
  float* out = (float*)d_out;                 // [4096,128] fp32

  char* ws = (char*)d_ws;
  u16* W1p  = (u16*)ws;                       //   262144 B
  u16* W2p  = (u16*)(ws + 262144);            //    65536 B
  u16* W1tp = (u16*)(ws + 327680);            //   262144 B  (total ~0.6 MB)

  k_prep<<<144, 256, 0, stream>>>(W1, W2, W1p, W2p, W1tp);
  k_all<<<256, 256, 0, stream>>>(obs, oth, W1p, W1tp, W2p, b1, b2, msk, out);
}